// Round 3
// baseline (285.665 us; speedup 1.0000x reference)
//
#include <hip/hip_runtime.h>
#include <math.h>

#define D     172
#define D4    43            // float4s per row
#define G3    516           // 3*D rows per weight matrix
#define RPB   8             // batch rows per GRU block
#define TPB   256
#define NGRU  512           // B/RPB
#define NCOPY 2048
#define WT_HALF (43 * 516)          // float4s per transposed matrix = 22188
#define WT_F4   (2 * WT_HALF)       // 44376
#define BMP_WORDS 15625             // ceil(500000/32)

typedef float vfloat4 __attribute__((ext_vector_type(4)));

// ---------------------------------------------------------------------------
// Prologue 1: transpose weights into ws as Wt[m][k4][row] (float4 over k),
// so GRU weight loads are coalesced across lanes (lane d -> consecutive f4).
// Also zeroes the touched-node bitmap.
// ---------------------------------------------------------------------------
__global__ __launch_bounds__(256) void prep_kernel(const float* __restrict__ w_ih,
                                                   const float* __restrict__ w_hh,
                                                   float4* __restrict__ wt,
                                                   unsigned* __restrict__ bmp) {
    int idx = blockIdx.x * 256 + threadIdx.x;
    if (idx < WT_F4) {
        int m   = idx / WT_HALF;
        int rem = idx - m * WT_HALF;
        int k4  = rem / G3;
        int row = rem - k4 * G3;
        const float* src = m ? w_hh : w_ih;
        wt[idx] = *(const float4*)(src + (long)row * D + 4 * k4);
    } else if (idx < WT_F4 + BMP_WORDS) {
        bmp[idx - WT_F4] = 0u;
    }
}

// Prologue 2: mark touched nodes (after zeroing completes).
__global__ __launch_bounds__(256) void mark_kernel(const int* __restrict__ ids,
                                                   unsigned* __restrict__ bmp, int B) {
    int i = blockIdx.x * 256 + threadIdx.x;
    if (i < B) {
        int id = ids[i];
        atomicOr(&bmp[id >> 5], 1u << (id & 31));
    }
}

// ---------------------------------------------------------------------------
// Fused kernel: blocks [0,NGRU) do the GRU for 8 batch rows each and scatter
// winner rows; blocks [NGRU, NGRU+NCOPY) grid-stride-copy every row whose
// bitmap bit is clear. Write sets are disjoint -> no inter-block ordering.
// ---------------------------------------------------------------------------
__global__ __launch_bounds__(TPB) void fused_kernel(
    const int*   __restrict__ ids,  const float* __restrict__ msg,
    const float* __restrict__ ts,   const float* __restrict__ mem,
    const float* __restrict__ lu,
    const float* __restrict__ b_ih, const float* __restrict__ b_hh,
    const float4* __restrict__ wt,  const unsigned* __restrict__ bmp,
    float* __restrict__ out_mem,    float* __restrict__ out_lu,
    int B, int N) {

    __shared__ float4 sxh[2][RPB][D4];   // [0]=x (messages), [1]=h (gathered memory)
    __shared__ int    s_id[RPB];
    __shared__ float  s_ts[RPB];
    __shared__ int    s_dup[RPB];

    const int tid = threadIdx.x;

    if (blockIdx.x < NGRU) {
        // ---------------- GRU part ----------------
        const int base = blockIdx.x * RPB;
        if (tid < RPB) {
            s_id[tid]  = ids[base + tid];
            s_ts[tid]  = ts[base + tid];
            s_dup[tid] = 0;
        }
        __syncthreads();

        // stage x and h rows as float4 (2*8*43 = 688 items)
        for (int it = tid; it < 2 * RPB * D4; it += TPB) {
            int which = it / (RPB * D4);
            int rem   = it - which * (RPB * D4);
            int r     = rem / D4;
            int k4    = rem - r * D4;
            const float* src = which ? (mem + (long)s_id[r] * D)
                                     : (msg + (long)(base + r) * D);
            ((float4*)sxh)[it] = *(const float4*)(src + 4 * k4);
        }
        // duplicate scan: row r loses if any later batch index has the same id
        for (int r = 0; r < RPB; ++r) {
            int my = s_id[r];
            for (int j = base + r + 1 + tid; j < B; j += TPB) {
                if (ids[j] == my) { s_dup[r] = 1; break; }
            }
        }
        __syncthreads();

        if (tid < D) {
            float acc[6][RPB];
            #pragma unroll
            for (int g = 0; g < 6; ++g)
                #pragma unroll
                for (int r = 0; r < RPB; ++r) acc[g][r] = 0.0f;

            const float4* wtB = wt + WT_HALF;
            for (int k4 = 0; k4 < D4; ++k4) {
                const int o = k4 * G3 + tid;
                float4 a0 = wt [o];
                float4 a1 = wt [o + D];
                float4 a2 = wt [o + 2 * D];
                float4 c0 = wtB[o];
                float4 c1 = wtB[o + D];
                float4 c2 = wtB[o + 2 * D];
                #pragma unroll
                for (int r = 0; r < RPB; ++r) {
                    float4 xv = sxh[0][r][k4];
                    float4 hv = sxh[1][r][k4];
                    acc[0][r] += a0.x * xv.x + a0.y * xv.y + a0.z * xv.z + a0.w * xv.w;
                    acc[1][r] += a1.x * xv.x + a1.y * xv.y + a1.z * xv.z + a1.w * xv.w;
                    acc[2][r] += a2.x * xv.x + a2.y * xv.y + a2.z * xv.z + a2.w * xv.w;
                    acc[3][r] += c0.x * hv.x + c0.y * hv.y + c0.z * hv.z + c0.w * hv.w;
                    acc[4][r] += c1.x * hv.x + c1.y * hv.y + c1.z * hv.z + c1.w * hv.w;
                    acc[5][r] += c2.x * hv.x + c2.y * hv.y + c2.z * hv.z + c2.w * hv.w;
                }
            }

            float bir = b_ih[tid], biz = b_ih[D + tid], bin_ = b_ih[2 * D + tid];
            float bhr = b_hh[tid], bhz = b_hh[D + tid], bhn  = b_hh[2 * D + tid];
            #pragma unroll
            for (int r = 0; r < RPB; ++r) {
                float i_r = acc[0][r] + bir;
                float i_z = acc[1][r] + biz;
                float i_n = acc[2][r] + bin_;
                float h_r = acc[3][r] + bhr;
                float h_z = acc[4][r] + bhz;
                float h_n = acc[5][r] + bhn;
                float rg = 1.0f / (1.0f + expf(-(i_r + h_r)));
                float zg = 1.0f / (1.0f + expf(-(i_z + h_z)));
                float ng = tanhf(i_n + rg * h_n);
                float hv = ((const float*)sxh[1][r])[tid];
                float outv = (1.0f - zg) * ng + zg * hv;
                if (!s_dup[r]) out_mem[(long)s_id[r] * D + tid] = outv;
            }
        }
        if (tid < RPB && !s_dup[tid]) out_lu[s_id[tid]] = s_ts[tid];
    } else {
        // ---------------- copy part (bitmap-skip) ----------------
        const unsigned cb = blockIdx.x - NGRU;
        const unsigned stride = NCOPY * TPB;
        const unsigned memf4 = (unsigned)N * D4;   // 21,500,000 < 2^31
        const vfloat4* mem4 = (const vfloat4*)mem;
        vfloat4* out4 = (vfloat4*)out_mem;
        for (unsigned i = cb * TPB + tid; i < memf4; i += stride) {
            unsigned row = i / 43u;
            unsigned word = bmp[row >> 5];
            if (!((word >> (row & 31u)) & 1u)) {
                vfloat4 v = __builtin_nontemporal_load(&mem4[i]);
                __builtin_nontemporal_store(v, &out4[i]);
            }
        }
        for (unsigned e = cb * TPB + tid; e < (unsigned)N; e += stride) {
            unsigned word = bmp[e >> 5];
            if (!((word >> (e & 31u)) & 1u)) {
                float v = __builtin_nontemporal_load(&lu[e]);
                __builtin_nontemporal_store(v, &out_lu[e]);
            }
        }
    }
}

extern "C" void kernel_launch(void* const* d_in, const int* in_sizes, int n_in,
                              void* d_out, int out_size, void* d_ws, size_t ws_size,
                              hipStream_t stream) {
    const int*   node_ids    = (const int*)d_in[0];
    const float* messages    = (const float*)d_in[1];
    const float* timestamps  = (const float*)d_in[2];
    const float* memory      = (const float*)d_in[3];
    const float* last_update = (const float*)d_in[4];
    const float* w_ih        = (const float*)d_in[5];
    const float* w_hh        = (const float*)d_in[6];
    const float* b_ih        = (const float*)d_in[7];
    const float* b_hh        = (const float*)d_in[8];
    float* out = (float*)d_out;

    const int B = in_sizes[0];          // 4096
    const int N = in_sizes[4];          // 500000
    const long memf = (long)N * D;

    float4*   wt  = (float4*)d_ws;
    unsigned* bmp = (unsigned*)((char*)d_ws + (size_t)WT_F4 * sizeof(float4));

    int prep_blocks = (WT_F4 + BMP_WORDS + 255) / 256;
    prep_kernel<<<prep_blocks, 256, 0, stream>>>(w_ih, w_hh, wt, bmp);
    mark_kernel<<<(B + 255) / 256, 256, 0, stream>>>(node_ids, bmp, B);
    fused_kernel<<<NGRU + NCOPY, TPB, 0, stream>>>(
        node_ids, messages, timestamps, memory, last_update,
        b_ih, b_hh, wt, bmp, out, out + memf, B, N);
}

// Round 4
// 225.113 us; speedup vs baseline: 1.2690x; 1.2690x over previous
//
#include <hip/hip_runtime.h>
#include <math.h>

#define D     172
#define D4    43            // float4s per row
#define G3    516           // 3*D rows per weight matrix
#define RPB   8             // batch rows per GRU block
#define TPB   256
#define NCOPY 2048
#define WT_HALF (43 * 516)          // float4s per transposed matrix = 22188
#define WT_F4   (2 * WT_HALF)       // 44376

typedef float vfloat4 __attribute__((ext_vector_type(4)));

// ---------------------------------------------------------------------------
// Prologue: transpose weights into ws as Wt[m][k4][row] (float4 over k),
// so GRU weight loads are coalesced across lanes (lane d -> consecutive f4).
// ---------------------------------------------------------------------------
__global__ __launch_bounds__(256) void prep_kernel(const float* __restrict__ w_ih,
                                                   const float* __restrict__ w_hh,
                                                   float4* __restrict__ wt) {
    int idx = blockIdx.x * 256 + threadIdx.x;
    if (idx < WT_F4) {
        int m   = idx / WT_HALF;
        int rem = idx - m * WT_HALF;
        int k4  = rem / G3;
        int row = rem - k4 * G3;
        const float* src = m ? w_hh : w_ih;
        wt[idx] = *(const float4*)(src + (long)row * D + 4 * k4);
    }
}

// ---------------------------------------------------------------------------
// Kernel 1: pure streaming copy, 4 independent loads in flight per thread.
// memory -> out[0:N*D], last_update -> out[N*D:N*D+N]. Branch-free inner
// body, no bitmap, no NT hints: this is the proven 6+ TB/s pattern.
// ---------------------------------------------------------------------------
__global__ __launch_bounds__(TPB) void copy_kernel(const vfloat4* __restrict__ mem4,
                                                   const vfloat4* __restrict__ lu4,
                                                   vfloat4* __restrict__ out4,
                                                   vfloat4* __restrict__ outlu4,
                                                   unsigned memf4, unsigned luf4) {
    const unsigned gid    = blockIdx.x * TPB + threadIdx.x;
    const unsigned stride = NCOPY * TPB;           // 524288

    for (unsigned i0 = gid; i0 < memf4; i0 += 4u * stride) {
        unsigned i1 = i0 + stride, i2 = i0 + 2u * stride, i3 = i0 + 3u * stride;
        vfloat4 v0, v1, v2, v3;
        v0 = mem4[i0];
        if (i1 < memf4) v1 = mem4[i1];
        if (i2 < memf4) v2 = mem4[i2];
        if (i3 < memf4) v3 = mem4[i3];
        out4[i0] = v0;
        if (i1 < memf4) out4[i1] = v1;
        if (i2 < memf4) out4[i2] = v2;
        if (i3 < memf4) out4[i3] = v3;
    }
    if (gid < luf4) outlu4[gid] = lu4[gid];        // 125000 f4s, single pass
}

// ---------------------------------------------------------------------------
// Kernel 2: GRU cell for 4096 touched rows + last-write-wins scatter.
// Runs after copy_kernel; overwrites the copied rows. Weights read from the
// transposed layout (coalesced). Dup suppression: row scatters only if no
// later batch index has the same node id.
// ---------------------------------------------------------------------------
__global__ __launch_bounds__(TPB) void gru_kernel(
    const int*   __restrict__ ids,  const float* __restrict__ msg,
    const float* __restrict__ ts,   const float* __restrict__ mem,
    const float* __restrict__ b_ih, const float* __restrict__ b_hh,
    const float4* __restrict__ wt,
    float* __restrict__ out_mem,    float* __restrict__ out_lu,
    int B) {

    __shared__ float4 sxh[2][RPB][D4];   // [0]=x (messages), [1]=h (gathered memory)
    __shared__ int    s_id[RPB];
    __shared__ float  s_ts[RPB];
    __shared__ int    s_dup[RPB];

    const int tid  = threadIdx.x;
    const int base = blockIdx.x * RPB;

    if (tid < RPB) {
        s_id[tid]  = ids[base + tid];
        s_ts[tid]  = ts[base + tid];
        s_dup[tid] = 0;
    }
    __syncthreads();

    for (int it = tid; it < 2 * RPB * D4; it += TPB) {
        int which = it / (RPB * D4);
        int rem   = it - which * (RPB * D4);
        int r     = rem / D4;
        int k4    = rem - r * D4;
        const float* src = which ? (mem + (long)s_id[r] * D)
                                 : (msg + (long)(base + r) * D);
        ((float4*)sxh)[it] = *(const float4*)(src + 4 * k4);
    }
    for (int r = 0; r < RPB; ++r) {
        int my = s_id[r];
        for (int j = base + r + 1 + tid; j < B; j += TPB) {
            if (ids[j] == my) { s_dup[r] = 1; break; }
        }
    }
    __syncthreads();

    if (tid < D) {
        float acc[6][RPB];
        #pragma unroll
        for (int g = 0; g < 6; ++g)
            #pragma unroll
            for (int r = 0; r < RPB; ++r) acc[g][r] = 0.0f;

        const float4* wtB = wt + WT_HALF;
        for (int k4 = 0; k4 < D4; ++k4) {
            const int o = k4 * G3 + tid;
            float4 a0 = wt [o];
            float4 a1 = wt [o + D];
            float4 a2 = wt [o + 2 * D];
            float4 c0 = wtB[o];
            float4 c1 = wtB[o + D];
            float4 c2 = wtB[o + 2 * D];
            #pragma unroll
            for (int r = 0; r < RPB; ++r) {
                float4 xv = sxh[0][r][k4];
                float4 hv = sxh[1][r][k4];
                acc[0][r] += a0.x * xv.x + a0.y * xv.y + a0.z * xv.z + a0.w * xv.w;
                acc[1][r] += a1.x * xv.x + a1.y * xv.y + a1.z * xv.z + a1.w * xv.w;
                acc[2][r] += a2.x * xv.x + a2.y * xv.y + a2.z * xv.z + a2.w * xv.w;
                acc[3][r] += c0.x * hv.x + c0.y * hv.y + c0.z * hv.z + c0.w * hv.w;
                acc[4][r] += c1.x * hv.x + c1.y * hv.y + c1.z * hv.z + c1.w * hv.w;
                acc[5][r] += c2.x * hv.x + c2.y * hv.y + c2.z * hv.z + c2.w * hv.w;
            }
        }

        float bir = b_ih[tid], biz = b_ih[D + tid], bin_ = b_ih[2 * D + tid];
        float bhr = b_hh[tid], bhz = b_hh[D + tid], bhn  = b_hh[2 * D + tid];
        #pragma unroll
        for (int r = 0; r < RPB; ++r) {
            float i_r = acc[0][r] + bir;
            float i_z = acc[1][r] + biz;
            float i_n = acc[2][r] + bin_;
            float h_r = acc[3][r] + bhr;
            float h_z = acc[4][r] + bhz;
            float h_n = acc[5][r] + bhn;
            float rg = 1.0f / (1.0f + expf(-(i_r + h_r)));
            float zg = 1.0f / (1.0f + expf(-(i_z + h_z)));
            float ng = tanhf(i_n + rg * h_n);
            float hv = ((const float*)sxh[1][r])[tid];
            float outv = (1.0f - zg) * ng + zg * hv;
            if (!s_dup[r]) out_mem[(long)s_id[r] * D + tid] = outv;
        }
    }
    if (tid < RPB && !s_dup[tid]) out_lu[s_id[tid]] = s_ts[tid];
}

extern "C" void kernel_launch(void* const* d_in, const int* in_sizes, int n_in,
                              void* d_out, int out_size, void* d_ws, size_t ws_size,
                              hipStream_t stream) {
    const int*   node_ids    = (const int*)d_in[0];
    const float* messages    = (const float*)d_in[1];
    const float* timestamps  = (const float*)d_in[2];
    const float* memory      = (const float*)d_in[3];
    const float* last_update = (const float*)d_in[4];
    const float* w_ih        = (const float*)d_in[5];
    const float* w_hh        = (const float*)d_in[6];
    const float* b_ih        = (const float*)d_in[7];
    const float* b_hh        = (const float*)d_in[8];
    float* out = (float*)d_out;

    const int B = in_sizes[0];          // 4096
    const int N = in_sizes[4];          // 500000
    const long memf = (long)N * D;      // 86,000,000 floats
    const unsigned memf4 = (unsigned)(memf / 4);
    const unsigned luf4  = (unsigned)(N / 4);

    float4* wt = (float4*)d_ws;

    prep_kernel<<<(WT_F4 + 255) / 256, 256, 0, stream>>>(w_ih, w_hh, wt);
    copy_kernel<<<NCOPY, TPB, 0, stream>>>((const vfloat4*)memory,
                                           (const vfloat4*)last_update,
                                           (vfloat4*)out,
                                           (vfloat4*)(out + memf),
                                           memf4, luf4);
    gru_kernel<<<B / RPB, TPB, 0, stream>>>(node_ids, messages, timestamps, memory,
                                            b_ih, b_hh, (const float4*)wt,
                                            out, out + memf, B);
}

// Round 6
// 218.580 us; speedup vs baseline: 1.3069x; 1.0299x over previous
//
#include <hip/hip_runtime.h>
#include <math.h>

#define D     172
#define D4    43            // float4s per row
#define G3    516           // 3*D rows per weight matrix
#define RPB   8             // batch rows per GRU block
#define TPB   256
#define NGRU  512           // B/RPB (B=4096)
#define NCOPY 2048
#define WT_HALF (43 * 516)          // float4s per transposed matrix = 22188
#define WT_F4   (2 * WT_HALF)       // 44376

typedef float vfloat4 __attribute__((ext_vector_type(4)));

// ---------------------------------------------------------------------------
// Prologue: transpose weights into ws as Wt[m][k4][row] (float4 over k) so
// GRU weight loads are coalesced across lanes (lane d -> consecutive f4).
// ---------------------------------------------------------------------------
__global__ __launch_bounds__(256) void prep_kernel(const float* __restrict__ w_ih,
                                                   const float* __restrict__ w_hh,
                                                   float4* __restrict__ wt) {
    int idx = blockIdx.x * 256 + threadIdx.x;
    if (idx < WT_F4) {
        int m   = idx / WT_HALF;
        int rem = idx - m * WT_HALF;
        int k4  = rem / G3;
        int row = rem - k4 * G3;
        const float* src = m ? w_hh : w_ih;
        wt[idx] = *(const float4*)(src + (long)row * D + 4 * k4);
    }
}

// ---------------------------------------------------------------------------
// GRU body: computes the 8 rows for this block, writes results CONTIGUOUSLY
// into gout (ws scratch) + per-row metadata. No writes to d_out -> can run
// concurrently with the copy blocks in the same kernel.
// Dup flag: shared-memory OR (any of the 256 threads may set it; benign
// race, all writers store 1). NOTE: __ballot is per-wave (64 lanes) on CDNA
// and must NOT be used for a 256-thread block reduction — that was R5's bug.
// ---------------------------------------------------------------------------
__device__ __forceinline__ void gru_block(
    int gblk,
    const int*   __restrict__ ids,  const float* __restrict__ msg,
    const float* __restrict__ ts,   const float* __restrict__ mem,
    const float* __restrict__ b_ih, const float* __restrict__ b_hh,
    const float4* __restrict__ wt,
    float* __restrict__ gout, int* __restrict__ g_id,
    float* __restrict__ g_ts, int* __restrict__ g_dup,
    int B) {

    __shared__ float4 sxh[2][RPB][D4];   // [0]=x (messages), [1]=h (gathered memory)
    __shared__ int    s_id[RPB];
    __shared__ int    s_dup[RPB];

    const int tid  = threadIdx.x;
    const int base = gblk * RPB;

    if (tid < RPB) {
        int id = ids[base + tid];
        s_id[tid]  = id;
        s_dup[tid] = 0;
        g_id[base + tid] = id;
        g_ts[base + tid] = ts[base + tid];
    }
    __syncthreads();

    for (int it = tid; it < 2 * RPB * D4; it += TPB) {
        int which = it / (RPB * D4);
        int rem   = it - which * (RPB * D4);
        int r     = rem / D4;
        int k4    = rem - r * D4;
        const float* src = which ? (mem + (long)s_id[r] * D)
                                 : (msg + (long)(base + r) * D);
        ((float4*)sxh)[it] = *(const float4*)(src + 4 * k4);
    }
    // duplicate scan: row r loses if any later batch index has the same id
    for (int r = 0; r < RPB; ++r) {
        int my = s_id[r];
        for (int j = base + r + 1 + tid; j < B; j += TPB) {
            if (ids[j] == my) { s_dup[r] = 1; break; }
        }
    }
    __syncthreads();
    if (tid < RPB) g_dup[base + tid] = s_dup[tid];

    if (tid < D) {
        float acc[6][RPB];
        #pragma unroll
        for (int g = 0; g < 6; ++g)
            #pragma unroll
            for (int r = 0; r < RPB; ++r) acc[g][r] = 0.0f;

        const float4* wtB = wt + WT_HALF;
        for (int k4 = 0; k4 < D4; ++k4) {
            const int o = k4 * G3 + tid;
            float4 a0 = wt [o];
            float4 a1 = wt [o + D];
            float4 a2 = wt [o + 2 * D];
            float4 c0 = wtB[o];
            float4 c1 = wtB[o + D];
            float4 c2 = wtB[o + 2 * D];
            #pragma unroll
            for (int r = 0; r < RPB; ++r) {
                float4 xv = sxh[0][r][k4];
                float4 hv = sxh[1][r][k4];
                acc[0][r] += a0.x * xv.x + a0.y * xv.y + a0.z * xv.z + a0.w * xv.w;
                acc[1][r] += a1.x * xv.x + a1.y * xv.y + a1.z * xv.z + a1.w * xv.w;
                acc[2][r] += a2.x * xv.x + a2.y * xv.y + a2.z * xv.z + a2.w * xv.w;
                acc[3][r] += c0.x * hv.x + c0.y * hv.y + c0.z * hv.z + c0.w * hv.w;
                acc[4][r] += c1.x * hv.x + c1.y * hv.y + c1.z * hv.z + c1.w * hv.w;
                acc[5][r] += c2.x * hv.x + c2.y * hv.y + c2.z * hv.z + c2.w * hv.w;
            }
        }

        float bir = b_ih[tid], biz = b_ih[D + tid], bin_ = b_ih[2 * D + tid];
        float bhr = b_hh[tid], bhz = b_hh[D + tid], bhn  = b_hh[2 * D + tid];
        #pragma unroll
        for (int r = 0; r < RPB; ++r) {
            float i_r = acc[0][r] + bir;
            float i_z = acc[1][r] + biz;
            float i_n = acc[2][r] + bin_;
            float h_r = acc[3][r] + bhr;
            float h_z = acc[4][r] + bhz;
            float h_n = acc[5][r] + bhn;
            float rg = 1.0f / (1.0f + expf(-(i_r + h_r)));
            float zg = 1.0f / (1.0f + expf(-(i_z + h_z)));
            float ng = tanhf(i_n + rg * h_n);
            float hv = ((const float*)sxh[1][r])[tid];
            gout[(long)(base + r) * D + tid] = (1.0f - zg) * ng + zg * hv;
        }
    }
}

// ---------------------------------------------------------------------------
// Fused kernel: blocks [0,NGRU) = GRU into scratch; blocks [NGRU,NGRU+NCOPY)
// = plain branch-free grid-stride float4 copy (the proven ~6.3 TB/s pattern).
// Write sets disjoint -> no inter-block ordering needed; GRU compute hides
// under the copy's HBM stream.
// ---------------------------------------------------------------------------
__global__ __launch_bounds__(TPB) void fused_kernel(
    const int*   __restrict__ ids,  const float* __restrict__ msg,
    const float* __restrict__ ts,   const float* __restrict__ mem,
    const float* __restrict__ lu,
    const float* __restrict__ b_ih, const float* __restrict__ b_hh,
    const float4* __restrict__ wt,
    float* __restrict__ gout, int* __restrict__ g_id,
    float* __restrict__ g_ts, int* __restrict__ g_dup,
    float* __restrict__ out_mem,    float* __restrict__ out_lu,
    int B, int N) {

    if (blockIdx.x < NGRU) {
        gru_block(blockIdx.x, ids, msg, ts, mem, b_ih, b_hh, wt,
                  gout, g_id, g_ts, g_dup, B);
        return;
    }
    const unsigned gid    = (blockIdx.x - NGRU) * TPB + threadIdx.x;
    const unsigned stride = NCOPY * TPB;
    const unsigned memf4  = (unsigned)N * D4;      // 21,500,000
    const vfloat4* mem4 = (const vfloat4*)mem;
    vfloat4* out4 = (vfloat4*)out_mem;
    for (unsigned i = gid; i < memf4; i += stride) out4[i] = mem4[i];
    const unsigned luf4 = (unsigned)N / 4;
    const vfloat4* lu4 = (const vfloat4*)lu;
    vfloat4* outlu4 = (vfloat4*)out_lu;
    for (unsigned i = gid; i < luf4; i += stride) outlu4[i] = lu4[i];
}

// ---------------------------------------------------------------------------
// Epilogue: scatter winner GRU rows + timestamps into the output (2.8 MB).
// ---------------------------------------------------------------------------
__global__ __launch_bounds__(TPB) void scatter_kernel(
    const float* __restrict__ gout, const int* __restrict__ g_id,
    const float* __restrict__ g_ts, const int* __restrict__ g_dup,
    float* __restrict__ out_mem, float* __restrict__ out_lu, int B) {
    int idx = blockIdx.x * TPB + threadIdx.x;
    int total = B * D;
    if (idx < total) {
        int r = idx / D;
        int d = idx - r * D;
        if (!g_dup[r]) out_mem[(long)g_id[r] * D + d] = gout[idx];
    } else if (idx < total + B) {
        int r = idx - total;
        if (!g_dup[r]) out_lu[g_id[r]] = g_ts[r];
    }
}

// ---------------- fallback (serial R4 path, used only if ws too small) -----
__global__ __launch_bounds__(TPB) void copy_kernel(const vfloat4* __restrict__ mem4,
                                                   const vfloat4* __restrict__ lu4,
                                                   vfloat4* __restrict__ out4,
                                                   vfloat4* __restrict__ outlu4,
                                                   unsigned memf4, unsigned luf4) {
    const unsigned gid    = blockIdx.x * TPB + threadIdx.x;
    const unsigned stride = NCOPY * TPB;
    for (unsigned i = gid; i < memf4; i += stride) out4[i] = mem4[i];
    for (unsigned i = gid; i < luf4; i += stride) outlu4[i] = lu4[i];
}

__global__ __launch_bounds__(TPB) void gru_direct_kernel(
    const int*   __restrict__ ids,  const float* __restrict__ msg,
    const float* __restrict__ ts,   const float* __restrict__ mem,
    const float* __restrict__ w_ih, const float* __restrict__ w_hh,
    const float* __restrict__ b_ih, const float* __restrict__ b_hh,
    float* __restrict__ out_mem,    float* __restrict__ out_lu, int B) {
    int r = blockIdx.x;
    int tid = threadIdx.x;
    __shared__ float sx[D], sh[D];
    __shared__ int s_id, s_dup;
    if (tid == 0) { s_id = ids[r]; s_dup = 0; }
    __syncthreads();
    if (tid < D) { sx[tid] = msg[(long)r * D + tid]; sh[tid] = mem[(long)s_id * D + tid]; }
    for (int j = r + 1 + tid; j < B; j += TPB) if (ids[j] == s_id) { s_dup = 1; break; }
    __syncthreads();
    if (s_dup) return;
    if (tid < D) {
        float a[6] = {0,0,0,0,0,0};
        for (int k = 0; k < D; ++k) {
            float xv = sx[k], hv = sh[k];
            a[0] += w_ih[(long)(0*D+tid)*D+k] * xv;
            a[1] += w_ih[(long)(1*D+tid)*D+k] * xv;
            a[2] += w_ih[(long)(2*D+tid)*D+k] * xv;
            a[3] += w_hh[(long)(0*D+tid)*D+k] * hv;
            a[4] += w_hh[(long)(1*D+tid)*D+k] * hv;
            a[5] += w_hh[(long)(2*D+tid)*D+k] * hv;
        }
        float rg = 1.0f / (1.0f + expf(-(a[0] + b_ih[tid] + a[3] + b_hh[tid])));
        float zg = 1.0f / (1.0f + expf(-(a[1] + b_ih[D+tid] + a[4] + b_hh[D+tid])));
        float ng = tanhf(a[2] + b_ih[2*D+tid] + rg * (a[5] + b_hh[2*D+tid]));
        out_mem[(long)s_id * D + tid] = (1.0f - zg) * ng + zg * sh[tid];
    }
    if (tid == 0) out_lu[s_id] = ts[r];
}

extern "C" void kernel_launch(void* const* d_in, const int* in_sizes, int n_in,
                              void* d_out, int out_size, void* d_ws, size_t ws_size,
                              hipStream_t stream) {
    const int*   node_ids    = (const int*)d_in[0];
    const float* messages    = (const float*)d_in[1];
    const float* timestamps  = (const float*)d_in[2];
    const float* memory      = (const float*)d_in[3];
    const float* last_update = (const float*)d_in[4];
    const float* w_ih        = (const float*)d_in[5];
    const float* w_hh        = (const float*)d_in[6];
    const float* b_ih        = (const float*)d_in[7];
    const float* b_hh        = (const float*)d_in[8];
    float* out = (float*)d_out;

    const int B = in_sizes[0];          // 4096
    const int N = in_sizes[4];          // 500000
    const long memf = (long)N * D;      // 86,000,000 floats

    // ws layout: wt | gout | g_id | g_ts | g_dup
    size_t off_wt   = 0;
    size_t off_gout = off_wt + (size_t)WT_F4 * 16;            // 710,016
    size_t off_id   = off_gout + (size_t)B * D * 4;           // +2,818,048
    size_t off_ts   = off_id + (size_t)B * 4;
    size_t off_dup  = off_ts + (size_t)B * 4;
    size_t ws_need  = off_dup + (size_t)B * 4;

    if (ws_size >= ws_need) {
        float4* wt    = (float4*)((char*)d_ws + off_wt);
        float*  gout  = (float*)((char*)d_ws + off_gout);
        int*    g_id  = (int*)((char*)d_ws + off_id);
        float*  g_ts  = (float*)((char*)d_ws + off_ts);
        int*    g_dup = (int*)((char*)d_ws + off_dup);

        prep_kernel<<<(WT_F4 + 255) / 256, 256, 0, stream>>>(w_ih, w_hh, wt);
        fused_kernel<<<NGRU + NCOPY, TPB, 0, stream>>>(
            node_ids, messages, timestamps, memory, last_update,
            b_ih, b_hh, (const float4*)wt,
            gout, g_id, g_ts, g_dup, out, out + memf, B, N);
        scatter_kernel<<<(B * D + B + TPB - 1) / TPB, TPB, 0, stream>>>(
            gout, g_id, g_ts, g_dup, out, out + memf, B);
    } else {
        copy_kernel<<<NCOPY, TPB, 0, stream>>>((const vfloat4*)memory,
                                               (const vfloat4*)last_update,
                                               (vfloat4*)out,
                                               (vfloat4*)(out + memf),
                                               (unsigned)(memf / 4), (unsigned)(N / 4));
        gru_direct_kernel<<<B, TPB, 0, stream>>>(node_ids, messages, timestamps, memory,
                                                 w_ih, w_hh, b_ih, b_hh,
                                                 out, out + memf, B);
    }
}

// Round 7
// 200.304 us; speedup vs baseline: 1.4262x; 1.0912x over previous
//
#include <hip/hip_runtime.h>
#include <math.h>

#define D     172
#define D4    43            // float4s per row
#define G3    516           // 3*D rows per weight matrix
#define RPB   8             // batch rows per GRU block
#define TPB   256
#define WT_HALF (43 * 516)          // float4s per transposed matrix = 22188
#define WT_F4   (2 * WT_HALF)       // 44376

typedef float vfloat4 __attribute__((ext_vector_type(4)));

// ---------------------------------------------------------------------------
// Prologue: transpose weights into ws as Wt[m][k4][row] (float4 over k) so
// GRU weight loads are coalesced across lanes (lane d -> consecutive f4).
// ---------------------------------------------------------------------------
__global__ __launch_bounds__(256) void prep_kernel(const float* __restrict__ w_ih,
                                                   const float* __restrict__ w_hh,
                                                   float4* __restrict__ wt) {
    int idx = blockIdx.x * 256 + threadIdx.x;
    if (idx < WT_F4) {
        int m   = idx / WT_HALF;
        int rem = idx - m * WT_HALF;
        int k4  = rem / G3;
        int row = rem - k4 * G3;
        const float* src = m ? w_hh : w_ih;
        wt[idx] = *(const float4*)(src + (long)row * D + 4 * k4);
    }
}

// ---------------------------------------------------------------------------
// GRU kernel (runs AFTER the bulk d2d copy): computes 8 batch rows per block
// and scatters winner rows + timestamps directly into the output. Dup
// suppression: shared-memory flag any thread may set (benign OR-race);
// NOTE: __ballot is per-wave (64 lanes) on CDNA — never use it for a
// 256-thread block reduction (R5's bug).
// ---------------------------------------------------------------------------
__global__ __launch_bounds__(TPB) void gru_kernel(
    const int*   __restrict__ ids,  const float* __restrict__ msg,
    const float* __restrict__ ts,   const float* __restrict__ mem,
    const float* __restrict__ b_ih, const float* __restrict__ b_hh,
    const float4* __restrict__ wt,
    float* __restrict__ out_mem,    float* __restrict__ out_lu,
    int B) {

    __shared__ float4 sxh[2][RPB][D4];   // [0]=x (messages), [1]=h (gathered memory)
    __shared__ int    s_id[RPB];
    __shared__ int    s_dup[RPB];

    const int tid  = threadIdx.x;
    const int base = blockIdx.x * RPB;

    if (tid < RPB) {
        s_id[tid]  = ids[base + tid];
        s_dup[tid] = 0;
    }
    __syncthreads();

    for (int it = tid; it < 2 * RPB * D4; it += TPB) {
        int which = it / (RPB * D4);
        int rem   = it - which * (RPB * D4);
        int r     = rem / D4;
        int k4    = rem - r * D4;
        const float* src = which ? (mem + (long)s_id[r] * D)
                                 : (msg + (long)(base + r) * D);
        ((float4*)sxh)[it] = *(const float4*)(src + 4 * k4);
    }
    // duplicate scan: row r loses if any later batch index has the same id
    for (int r = 0; r < RPB; ++r) {
        int my = s_id[r];
        for (int j = base + r + 1 + tid; j < B; j += TPB) {
            if (ids[j] == my) { s_dup[r] = 1; break; }
        }
    }
    __syncthreads();

    if (tid < D) {
        float acc[6][RPB];
        #pragma unroll
        for (int g = 0; g < 6; ++g)
            #pragma unroll
            for (int r = 0; r < RPB; ++r) acc[g][r] = 0.0f;

        const float4* wtB = wt + WT_HALF;
        for (int k4 = 0; k4 < D4; ++k4) {
            const int o = k4 * G3 + tid;
            float4 a0 = wt [o];
            float4 a1 = wt [o + D];
            float4 a2 = wt [o + 2 * D];
            float4 c0 = wtB[o];
            float4 c1 = wtB[o + D];
            float4 c2 = wtB[o + 2 * D];
            #pragma unroll
            for (int r = 0; r < RPB; ++r) {
                float4 xv = sxh[0][r][k4];
                float4 hv = sxh[1][r][k4];
                acc[0][r] += a0.x * xv.x + a0.y * xv.y + a0.z * xv.z + a0.w * xv.w;
                acc[1][r] += a1.x * xv.x + a1.y * xv.y + a1.z * xv.z + a1.w * xv.w;
                acc[2][r] += a2.x * xv.x + a2.y * xv.y + a2.z * xv.z + a2.w * xv.w;
                acc[3][r] += c0.x * hv.x + c0.y * hv.y + c0.z * hv.z + c0.w * hv.w;
                acc[4][r] += c1.x * hv.x + c1.y * hv.y + c1.z * hv.z + c1.w * hv.w;
                acc[5][r] += c2.x * hv.x + c2.y * hv.y + c2.z * hv.z + c2.w * hv.w;
            }
        }

        float bir = b_ih[tid], biz = b_ih[D + tid], bin_ = b_ih[2 * D + tid];
        float bhr = b_hh[tid], bhz = b_hh[D + tid], bhn  = b_hh[2 * D + tid];
        #pragma unroll
        for (int r = 0; r < RPB; ++r) {
            float i_r = acc[0][r] + bir;
            float i_z = acc[1][r] + biz;
            float i_n = acc[2][r] + bin_;
            float h_r = acc[3][r] + bhr;
            float h_z = acc[4][r] + bhz;
            float h_n = acc[5][r] + bhn;
            float rg = 1.0f / (1.0f + expf(-(i_r + h_r)));
            float zg = 1.0f / (1.0f + expf(-(i_z + h_z)));
            float ng = tanhf(i_n + rg * h_n);
            float hv = ((const float*)sxh[1][r])[tid];
            float outv = (1.0f - zg) * ng + zg * hv;
            if (!s_dup[r]) out_mem[(long)s_id[r] * D + tid] = outv;
        }
    }
    if (tid < RPB && !s_dup[tid]) out_lu[s_id[tid]] = ts[base + tid];
}

// ---------------- fallback GRU (uncoalesced weights, if ws too small) ------
__global__ __launch_bounds__(TPB) void gru_direct_kernel(
    const int*   __restrict__ ids,  const float* __restrict__ msg,
    const float* __restrict__ ts,   const float* __restrict__ mem,
    const float* __restrict__ w_ih, const float* __restrict__ w_hh,
    const float* __restrict__ b_ih, const float* __restrict__ b_hh,
    float* __restrict__ out_mem,    float* __restrict__ out_lu, int B) {
    int r = blockIdx.x;
    int tid = threadIdx.x;
    __shared__ float sx[D], sh[D];
    __shared__ int s_id, s_dup;
    if (tid == 0) { s_id = ids[r]; s_dup = 0; }
    __syncthreads();
    if (tid < D) { sx[tid] = msg[(long)r * D + tid]; sh[tid] = mem[(long)s_id * D + tid]; }
    for (int j = r + 1 + tid; j < B; j += TPB) if (ids[j] == s_id) { s_dup = 1; break; }
    __syncthreads();
    if (s_dup) return;
    if (tid < D) {
        float a[6] = {0,0,0,0,0,0};
        for (int k = 0; k < D; ++k) {
            float xv = sx[k], hv = sh[k];
            a[0] += w_ih[(long)(0*D+tid)*D+k] * xv;
            a[1] += w_ih[(long)(1*D+tid)*D+k] * xv;
            a[2] += w_ih[(long)(2*D+tid)*D+k] * xv;
            a[3] += w_hh[(long)(0*D+tid)*D+k] * hv;
            a[4] += w_hh[(long)(1*D+tid)*D+k] * hv;
            a[5] += w_hh[(long)(2*D+tid)*D+k] * hv;
        }
        float rg = 1.0f / (1.0f + expf(-(a[0] + b_ih[tid] + a[3] + b_hh[tid])));
        float zg = 1.0f / (1.0f + expf(-(a[1] + b_ih[D+tid] + a[4] + b_hh[D+tid])));
        float ng = tanhf(a[2] + b_ih[2*D+tid] + rg * (a[5] + b_hh[2*D+tid]));
        out_mem[(long)s_id * D + tid] = (1.0f - zg) * ng + zg * sh[tid];
    }
    if (tid == 0) out_lu[s_id] = ts[r];
}

extern "C" void kernel_launch(void* const* d_in, const int* in_sizes, int n_in,
                              void* d_out, int out_size, void* d_ws, size_t ws_size,
                              hipStream_t stream) {
    const int*   node_ids    = (const int*)d_in[0];
    const float* messages    = (const float*)d_in[1];
    const float* timestamps  = (const float*)d_in[2];
    const float* memory      = (const float*)d_in[3];
    const float* last_update = (const float*)d_in[4];
    const float* w_ih        = (const float*)d_in[5];
    const float* w_hh        = (const float*)d_in[6];
    const float* b_ih        = (const float*)d_in[7];
    const float* b_hh        = (const float*)d_in[8];
    float* out = (float*)d_out;

    const int B = in_sizes[0];          // 4096
    const int N = in_sizes[4];          // 500000
    const long memf = (long)N * D;      // 86,000,000 floats

    // Bulk copy via the runtime's tuned blit kernels (graph-capturable d2d).
    hipMemcpyAsync(out, memory, (size_t)memf * sizeof(float),
                   hipMemcpyDeviceToDevice, stream);
    hipMemcpyAsync(out + memf, last_update, (size_t)N * sizeof(float),
                   hipMemcpyDeviceToDevice, stream);

    const size_t wt_bytes = (size_t)WT_F4 * sizeof(float4);
    if (ws_size >= wt_bytes) {
        float4* wt = (float4*)d_ws;
        prep_kernel<<<(WT_F4 + 255) / 256, 256, 0, stream>>>(w_ih, w_hh, wt);
        gru_kernel<<<B / RPB, TPB, 0, stream>>>(node_ids, messages, timestamps, memory,
                                                b_ih, b_hh, (const float4*)wt,
                                                out, out + memf, B);
    } else {
        gru_direct_kernel<<<B, TPB, 0, stream>>>(node_ids, messages, timestamps, memory,
                                                 w_ih, w_hh, b_ih, b_hh,
                                                 out, out + memf, B);
    }
}